// Round 1
// baseline (6263.028 us; speedup 1.0000x reference)
//
#include <hip/hip_runtime.h>
#include <stdint.h>

// ---------------- problem dims ----------------
#define BB   64      // batch
#define TT   256     // timesteps
#define CIN  512
#define HH   1024
#define NBLK 192     // 64 L0 blocks + 128 L1 blocks
#define NTHR 256

// ---------------- workspace layout (bytes) ----------------
// All weight/x regions are pre-packed into MFMA fragment order:
//   frag chunk = 64 lanes x 16B; element (lane,e): value for
//   A: row=lane&15, k=(lane>>4)*8+e   B: col=lane&15, k=(lane>>4)*8+e
#define OFF_W0HH 0ull
#define SZ_W0HH  (64ull*32*4*64*16)      // [c][s32][f4][lane][16B] Whh0, 8 MB
#define OFF_W0IH (OFF_W0HH + SZ_W0HH)
#define SZ_W0IH  (64ull*16*4*64*16)      // [c][s16][f4][lane][16B] Wih0, 4 MB
#define OFF_W1   (OFF_W0IH + SZ_W0IH)
#define SZ_W1    (128ull*64*2*64*16)     // [c][s64][f2][lane][16B] Wih1;Whh1, 16 MB
#define OFF_XP   (OFF_W1 + SZ_W1)
#define SZ_XP    (256ull*16*4*64*16)     // [t][s16][hi4][b64][16B] x bf16, 16 MB
#define OFF_B0P  (OFF_XP + SZ_XP)        // [c][f4][16] f32
#define OFF_B1P  (OFF_B0P + 4096ull*4)   // [c][f2][16] f32
#define OFF_H0P  (OFF_B1P + 4096ull*4)   // 2 x 128KB ping-pong, frag layout
#define SZ_HP    131072ull               // [s32][hi4][b64][16B]
#define OFF_H1P  (OFF_H0P + 2*SZ_HP)
#define OFF_BAR  (OFF_H1P + 2*SZ_HP)
#define ZERO_SZ  (4*SZ_HP + 256)

typedef short bf16x8 __attribute__((ext_vector_type(8)));
typedef float f32x4 __attribute__((ext_vector_type(4)));

static __device__ __forceinline__ uint16_t f2b(float f) {
  union { float f; uint32_t u; } v; v.f = f;
  uint32_t r = (v.u + 0x7FFFu + ((v.u >> 16) & 1u)) >> 16;  // RNE
  return (uint16_t)r;
}
static __device__ __forceinline__ uint4 cvt8(const float* s) {
  uint4 o;
  o.x = (uint32_t)f2b(s[0]) | ((uint32_t)f2b(s[1]) << 16);
  o.y = (uint32_t)f2b(s[2]) | ((uint32_t)f2b(s[3]) << 16);
  o.z = (uint32_t)f2b(s[4]) | ((uint32_t)f2b(s[5]) << 16);
  o.w = (uint32_t)f2b(s[6]) | ((uint32_t)f2b(s[7]) << 16);
  return o;
}
static __device__ __forceinline__ f32x4 mfma16(uint4 a, uint4 b, f32x4 c) {
  return __builtin_amdgcn_mfma_f32_16x16x32_bf16(
      __builtin_bit_cast(bf16x8, a), __builtin_bit_cast(bf16x8, b), c, 0, 0, 0);
}
static __device__ __forceinline__ float sigm(float x)  { return 1.0f / (1.0f + __expf(-x)); }
static __device__ __forceinline__ float tanhx(float x) { return 1.0f - 2.0f / (__expf(2.0f * x) + 1.0f); }

// ---------------- pack kernels (run every call; ~45 MB of writes) ----------------
// Whh0 -> [c64][s32][f4][lane64][16B]; element = Whh0[f*1024 + c*16 + (lane&15)][s*32+(lane>>4)*8+e]
__global__ void pack_whh0(const float* __restrict__ w, char* __restrict__ ws) {
  uint32_t u = blockIdx.x * blockDim.x + threadIdx.x;           // 524288
  int lane = u & 63, f = (u >> 6) & 3, s = (u >> 8) & 31, c = u >> 13;
  int wrow = f * 1024 + c * 16 + (lane & 15);
  int k = s * 32 + (lane >> 4) * 8;
  ((uint4*)(ws + OFF_W0HH))[u] = cvt8(w + (size_t)wrow * 1024 + k);
}
__global__ void pack_wih0(const float* __restrict__ w, char* __restrict__ ws) {
  uint32_t u = blockIdx.x * blockDim.x + threadIdx.x;           // 262144
  int lane = u & 63, f = (u >> 6) & 3, s = (u >> 8) & 15, c = u >> 12;
  int wrow = f * 1024 + c * 16 + (lane & 15);
  int k = s * 32 + (lane >> 4) * 8;
  ((uint4*)(ws + OFF_W0IH))[u] = cvt8(w + (size_t)wrow * 512 + k);
}
// L1: cols packed per block as f=0:[i x8u | f x8u], f=1:[g x8u | o x8u]
__global__ void pack_w1(const float* __restrict__ wih, const float* __restrict__ whh,
                        char* __restrict__ ws) {
  uint32_t u = blockIdx.x * blockDim.x + threadIdx.x;           // 1048576
  int lane = u & 63, f = (u >> 6) & 1, s = (u >> 7) & 63, c = u >> 13;
  int col = lane & 15;
  int g = f * 2 + (col >> 3);
  int j = c * 8 + (col & 7);
  int wrow = g * 1024 + j;
  uint4 v;
  if (s < 32) v = cvt8(wih + (size_t)wrow * 1024 + s * 32 + (lane >> 4) * 8);
  else        v = cvt8(whh + (size_t)wrow * 1024 + (s - 32) * 32 + (lane >> 4) * 8);
  ((uint4*)(ws + OFF_W1))[u] = v;
}
// x [64][256][512] f32 -> [t][s16][hi4][b64][16B] bf16
__global__ void pack_x(const float* __restrict__ x, char* __restrict__ ws) {
  uint32_t u = blockIdx.x * blockDim.x + threadIdx.x;           // 1048576
  int b = u & 63, hi = (u >> 6) & 3, s = (u >> 8) & 15, t = u >> 12;
  int k = s * 32 + hi * 8;
  ((uint4*)(ws + OFF_XP))[u] = cvt8(x + (size_t)b * (TT * CIN) + t * CIN + k);
}
__global__ void pack_bias(const float* __restrict__ bih0, const float* __restrict__ bhh0,
                          const float* __restrict__ bih1, const float* __restrict__ bhh1,
                          char* __restrict__ ws) {
  uint32_t v = blockIdx.x * blockDim.x + threadIdx.x;           // 8192
  if (v < 4096) {
    int col = v & 15, f = (v >> 4) & 3, c = v >> 6;
    int idx = f * 1024 + c * 16 + col;
    ((float*)(ws + OFF_B0P))[v] = bih0[idx] + bhh0[idx];
  } else {
    uint32_t w = v - 4096;
    int col = w & 15, f = (w >> 4) & 1, c = w >> 5;
    int g = f * 2 + (col >> 3);
    int j = c * 8 + (col & 7);
    int idx = g * 1024 + j;
    ((float*)(ws + OFF_B1P))[w] = bih1[idx] + bhh1[idx];
  }
}

// ---------------- grid barrier ----------------
static __device__ __forceinline__ void gsync(uint32_t* bar, int p) {
  __syncthreads();
  if (threadIdx.x == 0) {
    __threadfence();                    // release: block's h-stores -> device scope
    atomicAdd(bar, 1u);                 // device-scope by default on CDNA
    uint32_t tgt = (uint32_t)NBLK * (uint32_t)(p + 1);
    while (__hip_atomic_load(bar, __ATOMIC_RELAXED, __HIP_MEMORY_SCOPE_AGENT) < tgt)
      __builtin_amdgcn_s_sleep(1);
    __threadfence();                    // acquire
  }
  __syncthreads();
}

// ---------------- persistent LSTM ----------------
// blocks 0..63: layer0, 16 hidden units each (64 gate cols, frags = i,f,g,o x 16u)
// blocks 64..191: layer1, 8 units each (32 gate cols, frags = [i|f]x8u, [g|o]x8u)
// phase p: L0 computes step t=p (p<256); L1 computes step t=p-1 (p>=1). 257 phases.
__global__ __launch_bounds__(NTHR, 1) void lstm_persist(char* __restrict__ ws,
                                                        float* __restrict__ out) {
  extern __shared__ char lds[];
  uint4* l4 = (uint4*)lds;
  const int tid = threadIdx.x, blk = blockIdx.x;
  const int wave = tid >> 6, lane = tid & 63;
  const int col = lane & 15, hi = lane >> 4;
  const int arow = 16 * wave + col;            // A-fragment row (batch)
  uint32_t* bar = (uint32_t*)(ws + OFF_BAR);
  const float* b0p = (const float*)(ws + OFF_B0P);
  const float* b1p = (const float*)(ws + OFF_B1P);

  if (blk < 64) {
    // ---------------- layer 0 ----------------
    const int c = blk;
    const uint4* wsrc = (const uint4*)(ws + OFF_W0HH + (size_t)c * 131072);
    for (int i = tid; i < 8192; i += NTHR) l4[i] = wsrc[i];
    __syncthreads();
    const uint4* wih = (const uint4*)(ws + OFF_W0IH + (size_t)c * 65536);
    const float bi = b0p[(c * 4 + 0) * 16 + col];
    const float bf = b0p[(c * 4 + 1) * 16 + col];
    const float bg = b0p[(c * 4 + 2) * 16 + col];
    const float bo = b0p[(c * 4 + 3) * 16 + col];
    float c0[4] = {0.f, 0.f, 0.f, 0.f};
    const int base16 = (c * 2 + (col >> 3)) * 64 + 16 * wave + hi * 4;  // h-write addr16 base

    for (int p = 0; p <= 256; ++p) {
      if (p < 256) {
        f32x4 a0 = {bi, bi, bi, bi}, a1 = {bf, bf, bf, bf};
        f32x4 a2 = {bg, bg, bg, bg}, a3 = {bo, bo, bo, bo};
        // input contribution: x(t) @ Wih0^T   (B streamed from global/L2)
        const uint4* xa = (const uint4*)(ws + OFF_XP + (size_t)p * 65536);
        #pragma unroll 4
        for (int s = 0; s < 16; ++s) {
          uint4 av = xa[(s * 4 + hi) * 64 + arow];
          uint4 b0 = wih[(s * 4 + 0) * 64 + lane];
          uint4 b1 = wih[(s * 4 + 1) * 64 + lane];
          uint4 b2 = wih[(s * 4 + 2) * 64 + lane];
          uint4 b3 = wih[(s * 4 + 3) * 64 + lane];
          a0 = mfma16(av, b0, a0); a1 = mfma16(av, b1, a1);
          a2 = mfma16(av, b2, a2); a3 = mfma16(av, b3, a3);
        }
        // recurrent: h0(t-1) @ Whh0^T  (B resident in LDS)
        const uint4* ha = (const uint4*)(ws + OFF_H0P + (size_t)((p + 1) & 1) * SZ_HP);
        #pragma unroll 4
        for (int s = 0; s < 32; ++s) {
          uint4 av = ha[(s * 4 + hi) * 64 + arow];
          uint4 b0 = l4[(s * 4 + 0) * 64 + lane];
          uint4 b1 = l4[(s * 4 + 1) * 64 + lane];
          uint4 b2 = l4[(s * 4 + 2) * 64 + lane];
          uint4 b3 = l4[(s * 4 + 3) * 64 + lane];
          a0 = mfma16(av, b0, a0); a1 = mfma16(av, b1, a1);
          a2 = mfma16(av, b2, a2); a3 = mfma16(av, b3, a3);
        }
        // elementwise + h write (c-state stays f32 in registers)
        uint16_t* hw = (uint16_t*)(ws + OFF_H0P + (size_t)(p & 1) * SZ_HP);
        #pragma unroll
        for (int r = 0; r < 4; ++r) {
          float iv = sigm(a0[r]), fv = sigm(a1[r]);
          float gv = tanhx(a2[r]), ov = sigm(a3[r]);
          c0[r] = fv * c0[r] + iv * gv;
          float hv = ov * tanhx(c0[r]);
          hw[(size_t)(base16 + r) * 8 + (col & 7)] = f2b(hv);
        }
      }
      gsync(bar, p);
    }
  } else {
    // ---------------- layer 1 ----------------
    const int c1 = blk - 64;
    const uint4* wsrc = (const uint4*)(ws + OFF_W1 + (size_t)c1 * 131072);
    for (int i = tid; i < 8192; i += NTHR) l4[i] = wsrc[i];
    __syncthreads();
    const float ba = b1p[(c1 * 2 + 0) * 16 + col];
    const float bb = b1p[(c1 * 2 + 1) * 16 + col];
    float c1s[4] = {0.f, 0.f, 0.f, 0.f};
    const int j = c1 * 8 + col;                       // unit (valid when col<8)
    const int base16 = c1 * 64 + 16 * wave + hi * 4;  // h1-write addr16 base

    for (int p = 0; p <= 256; ++p) {
      if (p >= 1) {
        f32x4 a0 = {ba, ba, ba, ba}, a1 = {bb, bb, bb, bb};
        // h0(t) @ Wih1^T
        const uint4* h0a = (const uint4*)(ws + OFF_H0P + (size_t)((p + 1) & 1) * SZ_HP);
        #pragma unroll 4
        for (int s = 0; s < 32; ++s) {
          uint4 av = h0a[(s * 4 + hi) * 64 + arow];
          uint4 b0 = l4[(s * 2 + 0) * 64 + lane];
          uint4 b1 = l4[(s * 2 + 1) * 64 + lane];
          a0 = mfma16(av, b0, a0); a1 = mfma16(av, b1, a1);
        }
        // h1(t-1) @ Whh1^T
        const uint4* h1a = (const uint4*)(ws + OFF_H1P + (size_t)(p & 1) * SZ_HP);
        #pragma unroll 4
        for (int s = 0; s < 32; ++s) {
          uint4 av = h1a[(s * 4 + hi) * 64 + arow];
          uint4 b0 = l4[((s + 32) * 2 + 0) * 64 + lane];
          uint4 b1 = l4[((s + 32) * 2 + 1) * 64 + lane];
          a0 = mfma16(av, b0, a0); a1 = mfma16(av, b1, a1);
        }
        // gate exchange: lane has {i,g} (col<8) or {f,o} (col>=8) of unit j
        uint16_t* hw = (uint16_t*)(ws + OFF_H1P + (size_t)((p + 1) & 1) * SZ_HP);
        #pragma unroll
        for (int r = 0; r < 4; ++r) {
          float fx = __shfl_xor(a0[r], 8);
          float ox = __shfl_xor(a1[r], 8);
          if (col < 8) {
            float iv = sigm(a0[r]), fv = sigm(fx);
            float gv = tanhx(a1[r]), ov = sigm(ox);
            c1s[r] = fv * c1s[r] + iv * gv;
            float hv = ov * tanhx(c1s[r]);
            hw[(size_t)(base16 + r) * 8 + col] = f2b(hv);
            if (p == 256) out[(size_t)(16 * wave + hi * 4 + r) * 1024 + j] = hv;
          }
        }
      }
      gsync(bar, p);
    }
  }
}

// ---------------- launcher ----------------
extern "C" void kernel_launch(void* const* d_in, const int* in_sizes, int n_in,
                              void* d_out, int out_size, void* d_ws, size_t ws_size,
                              hipStream_t stream) {
  const float* x    = (const float*)d_in[0];
  const float* Wih0 = (const float*)d_in[1];
  const float* Whh0 = (const float*)d_in[2];
  const float* bih0 = (const float*)d_in[3];
  const float* bhh0 = (const float*)d_in[4];
  const float* Wih1 = (const float*)d_in[5];
  const float* Whh1 = (const float*)d_in[6];
  const float* bih1 = (const float*)d_in[7];
  const float* bhh1 = (const float*)d_in[8];
  char* ws = (char*)d_ws;
  float* out = (float*)d_out;

  // zero h ping-pong buffers + barrier counter (captured into the graph)
  hipMemsetAsync(ws + OFF_H0P, 0, ZERO_SZ, stream);

  pack_whh0<<<2048, 256, 0, stream>>>(Whh0, ws);
  pack_wih0<<<1024, 256, 0, stream>>>(Wih0, ws);
  pack_w1  <<<4096, 256, 0, stream>>>(Wih1, Whh1, ws);
  pack_x   <<<4096, 256, 0, stream>>>(x, ws);
  pack_bias<<<32,   256, 0, stream>>>(bih0, bhh0, bih1, bhh1, ws);

  hipFuncSetAttribute((const void*)lstm_persist,
                      hipFuncAttributeMaxDynamicSharedMemorySize, 131072);
  void* args[] = {(void*)&ws, (void*)&out};
  hipLaunchCooperativeKernel((const void*)lstm_persist, dim3(NBLK), dim3(NTHR),
                             args, 131072, stream);
}